// Round 14
// baseline (292.226 us; speedup 1.0000x reference)
//
#include <hip/hip_runtime.h>
#include <math.h>

#define B 64
#define T 4096
#define H 256
#define D 128
#define O 128
#define EPS 1e-5f

#define TCHUNK 16    // t-chunks for context partials

typedef _Float16 half8 __attribute__((ext_vector_type(8)));
typedef float f32x4 __attribute__((ext_vector_type(4)));

__device__ __forceinline__ float tanh_fast(float x) {
  return 1.f - 2.f / (__expf(2.f * x) + 1.f);
}

// ---------------- K0: permute W_e into f16 MFMA-fragment order ----
__global__ __launch_bounds__(256) void k0_permW(const float* __restrict__ attn_W,
                                               _Float16* __restrict__ Bperm) {
  int idx = blockIdx.x * 256 + threadIdx.x;
  int j = idx & 7;
  int l = (idx >> 3) & 63;
  int kt = (idx >> 9) & 7;
  int nt = idx >> 12;
  int g = nt * 16 + (l & 15);
  int k = kt * 32 + ((l >> 4) << 3) + j;
  Bperm[idx] = (_Float16)attn_W[(size_t)g * (2 * H) + H + k];
}

// ---------------- K1 ----
__global__ __launch_bounds__(256) void k1_hidproj_gh(
    const float* __restrict__ last_hidden, const float* __restrict__ attn_W,
    const float* __restrict__ attn_b, const float* __restrict__ W_hh,
    const float* __restrict__ b_hh, float* __restrict__ hid_proj,
    float* __restrict__ gh) {
  int b = blockIdx.x;
  int g = threadIdx.x;
  __shared__ __align__(16) float hp[H];
  hp[g] = last_hidden[b * H + g];
  __syncthreads();
  const float4* hp4 = reinterpret_cast<const float4*>(hp);
  const float4* wr = reinterpret_cast<const float4*>(attn_W + (size_t)g * (2 * H));
  float acc = attn_b[g];
#pragma unroll 8
  for (int h4 = 0; h4 < H / 4; ++h4) {
    float4 w = wr[h4], x = hp4[h4];
    acc += w.x * x.x + w.y * x.y + w.z * x.z + w.w * x.w;
  }
  hid_proj[b * H + g] = acc;
#pragma unroll
  for (int k = 0; k < 3; ++k) {
    int row = k * H + g;
    const float4* whr = reinterpret_cast<const float4*>(W_hh + (size_t)row * H);
    float a2 = b_hh[row];
#pragma unroll 8
    for (int h4 = 0; h4 < H / 4; ++h4) {
      float4 w = whr[h4], x = hp4[h4];
      a2 += w.x * x.x + w.y * x.y + w.z * x.z + w.w * x.w;
    }
    gh[(size_t)b * (3 * H) + row] = a2;
  }
}

// ======== K2 pipelined: 512 thr, 4 chunks/block, LDS double-buffer ========
// Stage: ALL 8 float4 loads issued before use (1 HBM round-trip), then
// cvt+ds_write. Chunk c+1 loads issue before compute of chunk c -> latency
// hides under MFMA+epilogue. 2 barriers per chunk.
__global__ __launch_bounds__(512, 4) void k2_scores_pipe(
    const float* __restrict__ enc, const _Float16* __restrict__ Bperm,
    const float* __restrict__ hid_proj, const float* __restrict__ v,
    float* __restrict__ scores) {
  const int b = blockIdx.y;
  const int tid = threadIdx.x;
  const int wave = tid >> 6;   // 0..7
  const int lane = tid & 63;
  const int r = lane & 15;
  const int grp = lane >> 4;

  __shared__ __align__(16) _Float16 Alds[2][4 * 8 * 64 * 8];  // 2 x 32KB
  __shared__ float spart[8][64];

  // staging map: 512 threads cover 64 rows x 256 cols (8 float4 / thread)
  const int rbase = tid & 7;
  const int kg = (tid >> 3) & 31;
  const int ihi = (tid >> 8) & 1;
  const int kt_s = kg >> 2;
  const int lhi = (kg & 3) << 4;

  const int base_chunk = blockIdx.x * 4;

  float4 x0[4], x1[4];

  auto stage_load = [&](int c) {
    const int t0 = (base_chunk + c) * 64;
#pragma unroll
    for (int i = 0; i < 4; ++i) {
      int row = i * 16 + ihi * 8 + rbase;
      const float* src = enc + ((size_t)(t0 + row) * B + b) * H + kg * 8;
      x0[i] = *reinterpret_cast<const float4*>(src);
      x1[i] = *reinterpret_cast<const float4*>(src + 4);
    }
  };
  auto stage_write = [&](int buf) {
#pragma unroll
    for (int i = 0; i < 4; ++i) {
      int row = i * 16 + ihi * 8 + rbase;
      half8 hh;
      hh[0] = (_Float16)x0[i].x; hh[1] = (_Float16)x0[i].y;
      hh[2] = (_Float16)x0[i].z; hh[3] = (_Float16)x0[i].w;
      hh[4] = (_Float16)x1[i].x; hh[5] = (_Float16)x1[i].y;
      hh[6] = (_Float16)x1[i].z; hh[7] = (_Float16)x1[i].w;
      int m = row >> 4;
      int lane_s = lhi | (row & 15);
      *reinterpret_cast<half8*>(
          &Alds[buf][(((m * 8) + kt_s) * 64 + lane_s) * 8]) = hh;
    }
  };

  const half8* bp = reinterpret_cast<const half8*>(Bperm);
  const int ntb = wave * 2;

  float hpv[2], vg[2];
#pragma unroll
  for (int n = 0; n < 2; ++n) {
    int g = (ntb + n) * 16 + r;
    hpv[n] = hid_proj[b * H + g];
    vg[n] = v[g];
  }

  stage_load(0);
  stage_write(0);
  __syncthreads();

  for (int c = 0; c < 4; ++c) {
    const int buf = c & 1;
    if (c < 3) stage_load(c + 1);  // issue next chunk's loads early

    f32x4 acc[4][2];
#pragma unroll
    for (int m = 0; m < 4; ++m)
#pragma unroll
      for (int n = 0; n < 2; ++n) acc[m][n] = (f32x4){0.f, 0.f, 0.f, 0.f};

    half8 bB[2][2];
#pragma unroll
    for (int n = 0; n < 2; ++n) bB[0][n] = bp[((ntb + n) * 8 + 0) * 64 + lane];

#pragma unroll
    for (int kt = 0; kt < 8; ++kt) {
      if (kt < 7) {
#pragma unroll
        for (int n = 0; n < 2; ++n)
          bB[(kt + 1) & 1][n] = bp[((ntb + n) * 8 + kt + 1) * 64 + lane];
      }
#pragma unroll
      for (int m = 0; m < 4; ++m) {
        half8 a = *reinterpret_cast<const half8*>(
            &Alds[buf][((m * 8 + kt) * 64 + lane) * 8]);
#pragma unroll
        for (int n = 0; n < 2; ++n)
          acc[m][n] = __builtin_amdgcn_mfma_f32_16x16x32_f16(
              a, bB[kt & 1][n], acc[m][n], 0, 0, 0);
      }
    }

    // epilogue: v*tanh + reduce over this wave's 32 g, stash partials
#pragma unroll
    for (int m = 0; m < 4; ++m) {
#pragma unroll
      for (int i = 0; i < 4; ++i) {
        float s = 0.f;
#pragma unroll
        for (int n = 0; n < 2; ++n)
          s += vg[n] * tanh_fast(acc[m][n][i] + hpv[n]);
        s += __shfl_xor(s, 1);
        s += __shfl_xor(s, 2);
        s += __shfl_xor(s, 4);
        s += __shfl_xor(s, 8);
        if (r == 0) spart[wave][m * 16 + grp * 4 + i] = s;
      }
    }
    __syncthreads();  // spart ready; all LDS reads of buf complete
    if (tid < 64) {
      float sv = 0.f;
#pragma unroll
      for (int w = 0; w < 8; ++w) sv += spart[w][tid];
      scores[(size_t)b * T + (base_chunk + c) * 64 + tid] = sv;
    }
    if (c < 3) stage_write(buf ^ 1);  // waits on the early-issued loads
    __syncthreads();                  // next buffer visible
  }
}

// ---------------- K3: softmax over T per b (attn_weights output) ----
__global__ __launch_bounds__(256) void k3_softmax(
    const float* __restrict__ scores, float* __restrict__ attn_out) {
  int b = blockIdx.x;
  int tid = threadIdx.x;
  float vals[16];
  const float4* sp = reinterpret_cast<const float4*>(scores + (size_t)b * T);
#pragma unroll
  for (int i = 0; i < 4; ++i) {
    float4 x = sp[i * 256 + tid];
    vals[i * 4 + 0] = x.x; vals[i * 4 + 1] = x.y;
    vals[i * 4 + 2] = x.z; vals[i * 4 + 3] = x.w;
  }
  float m = -INFINITY;
#pragma unroll
  for (int i = 0; i < 16; ++i) m = fmaxf(m, vals[i]);
  for (int off = 32; off > 0; off >>= 1) m = fmaxf(m, __shfl_xor(m, off));
  __shared__ float redm[4];
  int wave = tid >> 6, lane = tid & 63;
  if (lane == 0) redm[wave] = m;
  __syncthreads();
  m = fmaxf(fmaxf(redm[0], redm[1]), fmaxf(redm[2], redm[3]));
  float s = 0.f;
#pragma unroll
  for (int i = 0; i < 16; ++i) {
    vals[i] = expf(vals[i] - m);
    s += vals[i];
  }
  for (int off = 32; off > 0; off >>= 1) s += __shfl_xor(s, off);
  __shared__ float reds[4];
  if (lane == 0) reds[wave] = s;
  __syncthreads();
  s = reds[0] + reds[1] + reds[2] + reds[3];
  float inv = 1.f / s;
  float4* op = reinterpret_cast<float4*>(attn_out + (size_t)b * T);
#pragma unroll
  for (int i = 0; i < 4; ++i) {
    float4 x;
    x.x = vals[i * 4 + 0] * inv; x.y = vals[i * 4 + 1] * inv;
    x.z = vals[i * 4 + 2] * inv; x.w = vals[i * 4 + 3] * inv;
    op[i * 256 + tid] = x;
  }
}

// ---------------- K4: context partials over t-chunks (f32) ----
__global__ __launch_bounds__(256) void k4_ctx_part(
    const float* __restrict__ enc, const float* __restrict__ attn_w,
    float* __restrict__ ctx_part) {
  int chunk = blockIdx.x;
  int b = blockIdx.y;
  int tid = threadIdx.x;
  int h4 = tid & 63;
  int tsub = tid >> 6;
  int tstart = chunk * (T / TCHUNK);
  float4 acc = {0.f, 0.f, 0.f, 0.f};
  const float* wrow = attn_w + (size_t)b * T;
#pragma unroll 8
  for (int t = tstart + tsub; t < tstart + T / TCHUNK; t += 4) {
    float w = wrow[t];
    float4 e = *reinterpret_cast<const float4*>(
        enc + ((size_t)t * B + b) * H + h4 * 4);
    acc.x += w * e.x; acc.y += w * e.y; acc.z += w * e.z; acc.w += w * e.w;
  }
  __shared__ float4 red[4][64];
  red[tsub][h4] = acc;
  __syncthreads();
  if (tid < 64) {
    float4 a = red[0][tid], b2 = red[1][tid], c = red[2][tid], d2 = red[3][tid];
    float4 r;
    r.x = a.x + b2.x + c.x + d2.x;
    r.y = a.y + b2.y + c.y + d2.y;
    r.z = a.z + b2.z + c.z + d2.z;
    r.w = a.w + b2.w + c.w + d2.w;
    *reinterpret_cast<float4*>(ctx_part + ((size_t)chunk * B + b) * H + tid * 4) = r;
  }
}

// ---------------- K5: sum chunks -> context, concat, pre-linear ----
__global__ __launch_bounds__(256) void k5_prelinear(
    const float* __restrict__ ctx_part, const float* __restrict__ motion,
    const float* __restrict__ pre_W, const float* __restrict__ pre_b,
    float* __restrict__ xpre) {
  int b = blockIdx.x;
  int g = threadIdx.x;
  __shared__ __align__(16) float cm[D + H];
  float c = 0.f;
#pragma unroll
  for (int p = 0; p < TCHUNK; ++p) c += ctx_part[((size_t)p * B + b) * H + g];
  cm[D + g] = c;
  if (g < D) cm[g] = motion[b * D + g];
  __syncthreads();
  const float4* cm4 = reinterpret_cast<const float4*>(cm);
  const float4* wr = reinterpret_cast<const float4*>(pre_W + (size_t)g * (D + H));
  float acc = pre_b[g];
#pragma unroll 8
  for (int j = 0; j < (D + H) / 4; ++j) {
    float4 w = wr[j], x = cm4[j];
    acc += w.x * x.x + w.y * x.y + w.z * x.z + w.w * x.w;
  }
  xpre[b * H + g] = acc;
}

// ---------------- K5b: batchnorm + relu ----
__global__ __launch_bounds__(256) void k5b_bn(
    const float* __restrict__ xpre, const float* __restrict__ gamma,
    const float* __restrict__ beta, float* __restrict__ xn) {
  int g = threadIdx.x;
  float mu = 0.f;
  for (int b = 0; b < B; ++b) mu += xpre[b * H + g];
  mu *= (1.f / B);
  float var = 0.f;
  for (int b = 0; b < B; ++b) {
    float d = xpre[b * H + g] - mu;
    var += d * d;
  }
  var *= (1.f / B);
  float sc = gamma[g] * rsqrtf(var + EPS);
  float bi = beta[g];
  for (int b = 0; b < B; ++b) {
    float y = (xpre[b * H + g] - mu) * sc + bi;
    xn[b * H + g] = fmaxf(y, 0.f);
  }
}

// ---------------- K6: GRU cell + output projection ----
__global__ __launch_bounds__(256) void k6_gru_out(
    const float* __restrict__ xn, const float* __restrict__ gh,
    const float* __restrict__ W_ih, const float* __restrict__ b_ih,
    const float* __restrict__ last_hidden, const float* __restrict__ out_W,
    const float* __restrict__ out_b, float* __restrict__ out_output,
    float* __restrict__ out_hidden) {
  int b = blockIdx.x;
  int g = threadIdx.x;
  __shared__ __align__(16) float xr[H];
  __shared__ __align__(16) float hn[H];
  xr[g] = xn[b * H + g];
  __syncthreads();
  const float4* xr4 = reinterpret_cast<const float4*>(xr);
  float gi[3];
#pragma unroll
  for (int k = 0; k < 3; ++k) {
    int row = k * H + g;
    const float4* wr = reinterpret_cast<const float4*>(W_ih + (size_t)row * H);
    float a = b_ih[row];
#pragma unroll 8
    for (int h4 = 0; h4 < H / 4; ++h4) {
      float4 w = wr[h4], x = xr4[h4];
      a += w.x * x.x + w.y * x.y + w.z * x.z + w.w * x.w;
    }
    gi[k] = a;
  }
  float hr = gh[(size_t)b * 3 * H + g];
  float hz = gh[(size_t)b * 3 * H + H + g];
  float hnn = gh[(size_t)b * 3 * H + 2 * H + g];
  float r = 1.f / (1.f + expf(-(gi[0] + hr)));
  float z = 1.f / (1.f + expf(-(gi[1] + hz)));
  float n = tanhf(gi[2] + r * hnn);
  float hprev = last_hidden[b * H + g];
  float hnew = (1.f - z) * n + z * hprev;
  out_hidden[b * H + g] = hnew;
  hn[g] = hnew;
  __syncthreads();
  if (g < O) {
    const float4* hn4 = reinterpret_cast<const float4*>(hn);
    const float4* wr = reinterpret_cast<const float4*>(out_W + (size_t)g * H);
    float a = out_b[g];
#pragma unroll 8
    for (int h4 = 0; h4 < H / 4; ++h4) {
      float4 w = wr[h4], x = hn4[h4];
      a += w.x * x.x + w.y * x.y + w.z * x.z + w.w * x.w;
    }
    out_output[b * O + g] = a;
  }
}

extern "C" void kernel_launch(void* const* d_in, const int* in_sizes, int n_in,
                              void* d_out, int out_size, void* d_ws,
                              size_t ws_size, hipStream_t stream) {
  (void)in_sizes; (void)n_in; (void)out_size; (void)ws_size;
  const float* motion      = (const float*)d_in[0];
  const float* last_hidden = (const float*)d_in[1];
  const float* enc         = (const float*)d_in[2];
  const float* attn_W      = (const float*)d_in[3];
  const float* attn_b      = (const float*)d_in[4];
  const float* v           = (const float*)d_in[5];
  const float* pre_W       = (const float*)d_in[6];
  const float* pre_b       = (const float*)d_in[7];
  const float* bn_g        = (const float*)d_in[8];
  const float* bn_b        = (const float*)d_in[9];
  const float* W_ih        = (const float*)d_in[10];
  const float* b_ih        = (const float*)d_in[11];
  const float* W_hh        = (const float*)d_in[12];
  const float* b_hh        = (const float*)d_in[13];
  const float* out_W       = (const float*)d_in[14];
  const float* out_b       = (const float*)d_in[15];

  float* out = (float*)d_out;
  float* out_output = out;
  float* out_hidden = out + B * O;
  float* out_attn   = out + B * O + B * H;

  float* ws = (float*)d_ws;
  float* sc = ws;                                   // B*T
  float* cp = sc + (size_t)B * T;                   // TCHUNK*B*H
  float* hp = cp + (size_t)TCHUNK * B * H;          // B*H
  float* gh = hp + (size_t)B * H;                   // 3*B*H
  float* xp = gh + (size_t)3 * B * H;               // B*H
  float* xn = xp + (size_t)B * H;                   // B*H
  _Float16* Bperm = (_Float16*)(xn + (size_t)B * H); // H*H f16

  k0_permW<<<256, 256, 0, stream>>>(attn_W, Bperm);
  k1_hidproj_gh<<<B, 256, 0, stream>>>(last_hidden, attn_W, attn_b, W_hh, b_hh,
                                       hp, gh);
  k2_scores_pipe<<<dim3(T / 256, B), 512, 0, stream>>>(enc, Bperm, hp, v, sc);
  k3_softmax<<<B, 256, 0, stream>>>(sc, out_attn);
  k4_ctx_part<<<dim3(TCHUNK, B), 256, 0, stream>>>(enc, out_attn, cp);
  k5_prelinear<<<B, 256, 0, stream>>>(cp, motion, pre_W, pre_b, xp);
  k5b_bn<<<1, 256, 0, stream>>>(xp, bn_g, bn_b, xn);
  k6_gru_out<<<B, 256, 0, stream>>>(xn, gh, W_ih, b_ih, last_hidden, out_W,
                                    out_b, out_output, out_hidden);
}

// Round 15
// 206.764 us; speedup vs baseline: 1.4133x; 1.4133x over previous
//
#include <hip/hip_runtime.h>
#include <math.h>

#define B 64
#define T 4096
#define H 256
#define D 128
#define O 128
#define EPS 1e-5f

#define TCHUNK 16    // t-chunks for k4 context partials
#define CHUNKS 8     // t-chunks per k2 block

typedef _Float16 half8 __attribute__((ext_vector_type(8)));
typedef float f32x4 __attribute__((ext_vector_type(4)));

__device__ __forceinline__ float tanh_fast(float x) {
  return 1.f - 2.f / (__expf(2.f * x) + 1.f);
}

// ---------------- K0: permute W_e into MFMA fragment order ----
// frag[(nt*8+kt)*64 + lane][j] = W_e[nt*16+(lane&15)][kt*32+(lane>>4)*8+j]
// (A- and B-fragment lane maps are identical, so this buffer serves as the
//  A-operand for the g-major orientation.)
__global__ __launch_bounds__(256) void k0_permW(const float* __restrict__ attn_W,
                                               _Float16* __restrict__ Bperm) {
  int idx = blockIdx.x * 256 + threadIdx.x;
  int j = idx & 7;
  int l = (idx >> 3) & 63;
  int kt = (idx >> 9) & 7;
  int nt = idx >> 12;
  int g = nt * 16 + (l & 15);
  int k = kt * 32 + ((l >> 4) << 3) + j;
  Bperm[idx] = (_Float16)attn_W[(size_t)g * (2 * H) + H + k];
}

// ---------------- K1 ----
__global__ __launch_bounds__(256) void k1_hidproj_gh(
    const float* __restrict__ last_hidden, const float* __restrict__ attn_W,
    const float* __restrict__ attn_b, const float* __restrict__ W_hh,
    const float* __restrict__ b_hh, float* __restrict__ hid_proj,
    float* __restrict__ gh) {
  int b = blockIdx.x;
  int g = threadIdx.x;
  __shared__ __align__(16) float hp[H];
  hp[g] = last_hidden[b * H + g];
  __syncthreads();
  const float4* hp4 = reinterpret_cast<const float4*>(hp);
  const float4* wr = reinterpret_cast<const float4*>(attn_W + (size_t)g * (2 * H));
  float acc = attn_b[g];
#pragma unroll 8
  for (int h4 = 0; h4 < H / 4; ++h4) {
    float4 w = wr[h4], x = hp4[h4];
    acc += w.x * x.x + w.y * x.y + w.z * x.z + w.w * x.w;
  }
  hid_proj[b * H + g] = acc;
#pragma unroll
  for (int k = 0; k < 3; ++k) {
    int row = k * H + g;
    const float4* whr = reinterpret_cast<const float4*>(W_hh + (size_t)row * H);
    float a2 = b_hh[row];
#pragma unroll 8
    for (int h4 = 0; h4 < H / 4; ++h4) {
      float4 w = whr[h4], x = hp4[h4];
      a2 += w.x * x.x + w.y * x.y + w.z * x.z + w.w * x.w;
    }
    gh[(size_t)b * (3 * H) + row] = a2;
  }
}

// ======== K2: W-in-registers persistent, g-major MFMA, enc streamed ========
// 512 thr / 8 waves; wave owns g-tiles nt = wave*2, wave*2+1 with W A-frags
// in 64 VGPRs loaded ONCE. Block sweeps 8 t-chunks; enc tile staged into
// double-buffered LDS (B-fragments). Steady-state global traffic = enc only.
__global__ __launch_bounds__(512, 3) void k2_scores_wreg(
    const float* __restrict__ enc, const _Float16* __restrict__ Bperm,
    const float* __restrict__ hid_proj, const float* __restrict__ v,
    float* __restrict__ scores) {
  const int b = blockIdx.y;
  const int tid = threadIdx.x;
  const int wave = tid >> 6;   // 0..7
  const int lane = tid & 63;
  const int r = lane & 15;
  const int grp = lane >> 4;

  __shared__ __align__(16) _Float16 Alds[2][4 * 8 * 64 * 8];  // 2 x 32KB
  __shared__ float spart[8][64];

  // ---- persistent W A-fragments (2 nt x 8 kt), loaded once ----
  const half8* bp = reinterpret_cast<const half8*>(Bperm);
  const int ntb = wave * 2;
  half8 wfrag[2][8];
#pragma unroll
  for (int n = 0; n < 2; ++n)
#pragma unroll
    for (int kt = 0; kt < 8; ++kt)
      wfrag[n][kt] = bp[((ntb + n) * 8 + kt) * 64 + lane];

  // hpv/vg for this lane's 8 g values: g = (ntb+n)*16 + grp*4 + i
  float hpv[2][4], vg[2][4];
#pragma unroll
  for (int n = 0; n < 2; ++n)
#pragma unroll
    for (int i = 0; i < 4; ++i) {
      int g = (ntb + n) * 16 + grp * 4 + i;
      hpv[n][i] = hid_proj[b * H + g];
      vg[n][i] = v[g];
    }

  // staging map (validated in R13): 512 thr cover 64 rows x 256 cols
  const int rbase = tid & 7;
  const int kg = (tid >> 3) & 31;
  const int ihi = (tid >> 8) & 1;
  const int kt_s = kg >> 2;
  const int lhi = (kg & 3) << 4;
  const int cbase = blockIdx.x * CHUNKS;

  float4 x0[4], x1[4];
  auto stage_load = [&](int c) {
    const int t0 = (cbase + c) * 64;
#pragma unroll
    for (int i = 0; i < 4; ++i) {
      int row = i * 16 + ihi * 8 + rbase;
      const float* src = enc + ((size_t)(t0 + row) * B + b) * H + kg * 8;
      x0[i] = *reinterpret_cast<const float4*>(src);
      x1[i] = *reinterpret_cast<const float4*>(src + 4);
    }
  };
  auto stage_write = [&](int buf) {
#pragma unroll
    for (int i = 0; i < 4; ++i) {
      int row = i * 16 + ihi * 8 + rbase;
      half8 hh;
      hh[0] = (_Float16)x0[i].x; hh[1] = (_Float16)x0[i].y;
      hh[2] = (_Float16)x0[i].z; hh[3] = (_Float16)x0[i].w;
      hh[4] = (_Float16)x1[i].x; hh[5] = (_Float16)x1[i].y;
      hh[6] = (_Float16)x1[i].z; hh[7] = (_Float16)x1[i].w;
      int m = row >> 4;
      int lane_s = lhi | (row & 15);
      *reinterpret_cast<half8*>(
          &Alds[buf][(((m * 8) + kt_s) * 64 + lane_s) * 8]) = hh;
    }
  };

  stage_load(0);
  stage_write(0);
  __syncthreads();

  for (int c = 0; c < CHUNKS; ++c) {
    const int buf = c & 1;

    // ---- k-loop: pure LDS + MFMA (W from registers) ----
    f32x4 acc[2][4];
#pragma unroll
    for (int n = 0; n < 2; ++n)
#pragma unroll
      for (int m = 0; m < 4; ++m) acc[n][m] = (f32x4){0.f, 0.f, 0.f, 0.f};

#pragma unroll
    for (int kt = 0; kt < 8; ++kt) {
#pragma unroll
      for (int m = 0; m < 4; ++m) {
        half8 e = *reinterpret_cast<const half8*>(
            &Alds[buf][((m * 8 + kt) * 64 + lane) * 8]);
        acc[0][m] = __builtin_amdgcn_mfma_f32_16x16x32_f16(
            wfrag[0][kt], e, acc[0][m], 0, 0, 0);
        acc[1][m] = __builtin_amdgcn_mfma_f32_16x16x32_f16(
            wfrag[1][kt], e, acc[1][m], 0, 0, 0);
      }
    }

    // issue next chunk's loads now; they complete under the epilogue
    if (c + 1 < CHUNKS) stage_load(c + 1);

    // ---- epilogue: D[g,t] -> s(t) = sum_g v*tanh(E+hp) ----
#pragma unroll
    for (int m = 0; m < 4; ++m) {
      float s = 0.f;
#pragma unroll
      for (int n = 0; n < 2; ++n)
#pragma unroll
        for (int i = 0; i < 4; ++i)
          s += vg[n][i] * tanh_fast(acc[n][m][i] + hpv[n][i]);
      s += __shfl_xor(s, 16);
      s += __shfl_xor(s, 32);
      if (grp == 0) spart[wave][m * 16 + r] = s;
    }
    __syncthreads();
    if (tid < 64) {
      float sv = 0.f;
#pragma unroll
      for (int w = 0; w < 8; ++w) sv += spart[w][tid];
      scores[(size_t)b * T + (cbase + c) * 64 + tid] = sv;
    }
    if (c + 1 < CHUNKS) stage_write(buf ^ 1);
    __syncthreads();
  }
}

// ---------------- K3: softmax over T per b (attn_weights output) ----
__global__ __launch_bounds__(256) void k3_softmax(
    const float* __restrict__ scores, float* __restrict__ attn_out) {
  int b = blockIdx.x;
  int tid = threadIdx.x;
  float vals[16];
  const float4* sp = reinterpret_cast<const float4*>(scores + (size_t)b * T);
#pragma unroll
  for (int i = 0; i < 4; ++i) {
    float4 x = sp[i * 256 + tid];
    vals[i * 4 + 0] = x.x; vals[i * 4 + 1] = x.y;
    vals[i * 4 + 2] = x.z; vals[i * 4 + 3] = x.w;
  }
  float m = -INFINITY;
#pragma unroll
  for (int i = 0; i < 16; ++i) m = fmaxf(m, vals[i]);
  for (int off = 32; off > 0; off >>= 1) m = fmaxf(m, __shfl_xor(m, off));
  __shared__ float redm[4];
  int wave = tid >> 6, lane = tid & 63;
  if (lane == 0) redm[wave] = m;
  __syncthreads();
  m = fmaxf(fmaxf(redm[0], redm[1]), fmaxf(redm[2], redm[3]));
  float s = 0.f;
#pragma unroll
  for (int i = 0; i < 16; ++i) {
    vals[i] = expf(vals[i] - m);
    s += vals[i];
  }
  for (int off = 32; off > 0; off >>= 1) s += __shfl_xor(s, off);
  __shared__ float reds[4];
  if (lane == 0) reds[wave] = s;
  __syncthreads();
  s = reds[0] + reds[1] + reds[2] + reds[3];
  float inv = 1.f / s;
  float4* op = reinterpret_cast<float4*>(attn_out + (size_t)b * T);
#pragma unroll
  for (int i = 0; i < 4; ++i) {
    float4 x;
    x.x = vals[i * 4 + 0] * inv; x.y = vals[i * 4 + 1] * inv;
    x.z = vals[i * 4 + 2] * inv; x.w = vals[i * 4 + 3] * inv;
    op[i * 256 + tid] = x;
  }
}

// ---------------- K4: context partials over t-chunks (f32) ----
__global__ __launch_bounds__(256) void k4_ctx_part(
    const float* __restrict__ enc, const float* __restrict__ attn_w,
    float* __restrict__ ctx_part) {
  int chunk = blockIdx.x;
  int b = blockIdx.y;
  int tid = threadIdx.x;
  int h4 = tid & 63;
  int tsub = tid >> 6;
  int tstart = chunk * (T / TCHUNK);
  float4 acc = {0.f, 0.f, 0.f, 0.f};
  const float* wrow = attn_w + (size_t)b * T;
#pragma unroll 8
  for (int t = tstart + tsub; t < tstart + T / TCHUNK; t += 4) {
    float w = wrow[t];
    float4 e = *reinterpret_cast<const float4*>(
        enc + ((size_t)t * B + b) * H + h4 * 4);
    acc.x += w * e.x; acc.y += w * e.y; acc.z += w * e.z; acc.w += w * e.w;
  }
  __shared__ float4 red[4][64];
  red[tsub][h4] = acc;
  __syncthreads();
  if (tid < 64) {
    float4 a = red[0][tid], b2 = red[1][tid], c = red[2][tid], d2 = red[3][tid];
    float4 r;
    r.x = a.x + b2.x + c.x + d2.x;
    r.y = a.y + b2.y + c.y + d2.y;
    r.z = a.z + b2.z + c.z + d2.z;
    r.w = a.w + b2.w + c.w + d2.w;
    *reinterpret_cast<float4*>(ctx_part + ((size_t)chunk * B + b) * H + tid * 4) = r;
  }
}

// ---------------- K5: sum chunks -> context, concat, pre-linear ----
__global__ __launch_bounds__(256) void k5_prelinear(
    const float* __restrict__ ctx_part, const float* __restrict__ motion,
    const float* __restrict__ pre_W, const float* __restrict__ pre_b,
    float* __restrict__ xpre) {
  int b = blockIdx.x;
  int g = threadIdx.x;
  __shared__ __align__(16) float cm[D + H];
  float c = 0.f;
#pragma unroll
  for (int p = 0; p < TCHUNK; ++p) c += ctx_part[((size_t)p * B + b) * H + g];
  cm[D + g] = c;
  if (g < D) cm[g] = motion[b * D + g];
  __syncthreads();
  const float4* cm4 = reinterpret_cast<const float4*>(cm);
  const float4* wr = reinterpret_cast<const float4*>(pre_W + (size_t)g * (D + H));
  float acc = pre_b[g];
#pragma unroll 8
  for (int j = 0; j < (D + H) / 4; ++j) {
    float4 w = wr[j], x = cm4[j];
    acc += w.x * x.x + w.y * x.y + w.z * x.z + w.w * x.w;
  }
  xpre[b * H + g] = acc;
}

// ---------------- K5b: batchnorm + relu ----
__global__ __launch_bounds__(256) void k5b_bn(
    const float* __restrict__ xpre, const float* __restrict__ gamma,
    const float* __restrict__ beta, float* __restrict__ xn) {
  int g = threadIdx.x;
  float mu = 0.f;
  for (int b = 0; b < B; ++b) mu += xpre[b * H + g];
  mu *= (1.f / B);
  float var = 0.f;
  for (int b = 0; b < B; ++b) {
    float d = xpre[b * H + g] - mu;
    var += d * d;
  }
  var *= (1.f / B);
  float sc = gamma[g] * rsqrtf(var + EPS);
  float bi = beta[g];
  for (int b = 0; b < B; ++b) {
    float y = (xpre[b * H + g] - mu) * sc + bi;
    xn[b * H + g] = fmaxf(y, 0.f);
  }
}

// ---------------- K6: GRU cell + output projection ----
__global__ __launch_bounds__(256) void k6_gru_out(
    const float* __restrict__ xn, const float* __restrict__ gh,
    const float* __restrict__ W_ih, const float* __restrict__ b_ih,
    const float* __restrict__ last_hidden, const float* __restrict__ out_W,
    const float* __restrict__ out_b, float* __restrict__ out_output,
    float* __restrict__ out_hidden) {
  int b = blockIdx.x;
  int g = threadIdx.x;
  __shared__ __align__(16) float xr[H];
  __shared__ __align__(16) float hn[H];
  xr[g] = xn[b * H + g];
  __syncthreads();
  const float4* xr4 = reinterpret_cast<const float4*>(xr);
  float gi[3];
#pragma unroll
  for (int k = 0; k < 3; ++k) {
    int row = k * H + g;
    const float4* wr = reinterpret_cast<const float4*>(W_ih + (size_t)row * H);
    float a = b_ih[row];
#pragma unroll 8
    for (int h4 = 0; h4 < H / 4; ++h4) {
      float4 w = wr[h4], x = xr4[h4];
      a += w.x * x.x + w.y * x.y + w.z * x.z + w.w * x.w;
    }
    gi[k] = a;
  }
  float hr = gh[(size_t)b * 3 * H + g];
  float hz = gh[(size_t)b * 3 * H + H + g];
  float hnn = gh[(size_t)b * 3 * H + 2 * H + g];
  float r = 1.f / (1.f + expf(-(gi[0] + hr)));
  float z = 1.f / (1.f + expf(-(gi[1] + hz)));
  float n = tanhf(gi[2] + r * hnn);
  float hprev = last_hidden[b * H + g];
  float hnew = (1.f - z) * n + z * hprev;
  out_hidden[b * H + g] = hnew;
  hn[g] = hnew;
  __syncthreads();
  if (g < O) {
    const float4* hn4 = reinterpret_cast<const float4*>(hn);
    const float4* wr = reinterpret_cast<const float4*>(out_W + (size_t)g * H);
    float a = out_b[g];
#pragma unroll 8
    for (int h4 = 0; h4 < H / 4; ++h4) {
      float4 w = wr[h4], x = hn4[h4];
      a += w.x * x.x + w.y * x.y + w.z * x.z + w.w * x.w;
    }
    out_output[b * O + g] = a;
  }
}

extern "C" void kernel_launch(void* const* d_in, const int* in_sizes, int n_in,
                              void* d_out, int out_size, void* d_ws,
                              size_t ws_size, hipStream_t stream) {
  (void)in_sizes; (void)n_in; (void)out_size; (void)ws_size;
  const float* motion      = (const float*)d_in[0];
  const float* last_hidden = (const float*)d_in[1];
  const float* enc         = (const float*)d_in[2];
  const float* attn_W      = (const float*)d_in[3];
  const float* attn_b      = (const float*)d_in[4];
  const float* v           = (const float*)d_in[5];
  const float* pre_W       = (const float*)d_in[6];
  const float* pre_b       = (const float*)d_in[7];
  const float* bn_g        = (const float*)d_in[8];
  const float* bn_b        = (const float*)d_in[9];
  const float* W_ih        = (const float*)d_in[10];
  const float* b_ih        = (const float*)d_in[11];
  const float* W_hh        = (const float*)d_in[12];
  const float* b_hh        = (const float*)d_in[13];
  const float* out_W       = (const float*)d_in[14];
  const float* out_b       = (const float*)d_in[15];

  float* out = (float*)d_out;
  float* out_output = out;
  float* out_hidden = out + B * O;
  float* out_attn   = out + B * O + B * H;

  float* ws = (float*)d_ws;
  float* sc = ws;                                   // B*T
  float* cp = sc + (size_t)B * T;                   // TCHUNK*B*H
  float* hp = cp + (size_t)TCHUNK * B * H;          // B*H
  float* gh = hp + (size_t)B * H;                   // 3*B*H
  float* xp = gh + (size_t)3 * B * H;               // B*H
  float* xn = xp + (size_t)B * H;                   // B*H
  _Float16* Bperm = (_Float16*)(xn + (size_t)B * H); // H*H f16

  k0_permW<<<256, 256, 0, stream>>>(attn_W, Bperm);
  k1_hidproj_gh<<<B, 256, 0, stream>>>(last_hidden, attn_W, attn_b, W_hh, b_hh,
                                       hp, gh);
  k2_scores_wreg<<<dim3(T / (64 * CHUNKS), B), 512, 0, stream>>>(enc, Bperm,
                                                                 hp, v, sc);
  k3_softmax<<<B, 256, 0, stream>>>(sc, out_attn);
  k4_ctx_part<<<dim3(TCHUNK, B), 256, 0, stream>>>(enc, out_attn, cp);
  k5_prelinear<<<B, 256, 0, stream>>>(cp, motion, pre_W, pre_b, xp);
  k5b_bn<<<1, 256, 0, stream>>>(xp, bn_g, bn_b, xn);
  k6_gru_out<<<B, 256, 0, stream>>>(xn, gh, W_ih, b_ih, last_hidden, out_W,
                                    out_b, out_output, out_hidden);
}